// Round 10
// baseline (155.079 us; speedup 1.0000x reference)
//
#include <hip/hip_runtime.h>
#include <hip/hip_cooperative_groups.h>

// SNN autoencoder collapses to: m_e = x @ enc_w ; m_d = m_e @ dec_w
// (spike state is exactly {0,1}, so 0.9*s - 0.9*(s>0.9) == 0 every step;
//  membranes are recomputed from the constant input current each step).
// Output: d_out = [m_d (2048x1024) | m_e (2048x256)], fp32.
//
// ONE cooperative dispatch (512 blocks x 256 thr, 80 KB LDS, 2 blocks/CU):
//   phase P: prep units (x->bf16, enc/dec transpose), 3 units/block
//   grid.sync()
//   phase 1: gemm1 tile (32x32, BK=256, dbuf)  [r8-proven body]
//   grid.sync()
//   phase 2: gemm2 tile (32x128, K=256 LDS-resident) [r8-proven body]
// Fine-grained per-tile release/acquire (r9) forced per-tile L2 flushes on
// multi-XCD CDNA4 and ran 53us; grid.sync amortizes to 2 fences total.
// Host falls back to the r8 3-dispatch path if cooperative launch errors.

namespace cg = cooperative_groups;

typedef __attribute__((ext_vector_type(8))) short bf16x8;
typedef __attribute__((ext_vector_type(4))) float f32x4;
typedef __attribute__((ext_vector_type(8))) unsigned short ushort8;

__device__ __forceinline__ unsigned short f2bf(float f) {
    unsigned u = __builtin_bit_cast(unsigned, f);
    unsigned r = u + 0x7FFFu + ((u >> 16) & 1u);   // RNE
    return (unsigned short)(r >> 16);
}

__device__ __forceinline__ void gload_lds16(const void* src, void* dst) {
    __builtin_amdgcn_global_load_lds(
        (const __attribute__((address_space(1))) void*)src,
        (__attribute__((address_space(3))) void*)dst, 16, 0, 0);
}

// ---- stage ROWS x 64 bf16 tile (8 chunks/row, XOR-swizzled source, rule #21) ----
template <int ROWS>
__device__ __forceinline__ void stage_tile(const unsigned short* __restrict__ g,
                                           int ld, unsigned short* lds, int t) {
    #pragma unroll
    for (int c = 0; c < ROWS / 32; ++c) {
        const int idx = c * 256 + t;          // 16B-chunk index in tile
        const int row = idx >> 3;
        const int chunk = (idx & 7) ^ (row & 7);
        const unsigned short* src = g + (size_t)row * ld + chunk * 8;
        unsigned short* dst = lds + (size_t)(idx & ~63) * 8;  // wave-uniform base
        gload_lds16(src, dst);
    }
}

// ---- one prep unit: unit<1024 x-cvt | 1024..1279 encT | 1280..1535 decT ----
__device__ __forceinline__ void prep_unit(
    int unit, int t, unsigned short (*tile)[33],
    const float* __restrict__ x, const float* __restrict__ enc,
    const float* __restrict__ dec, unsigned short* __restrict__ x_bf,
    unsigned short* __restrict__ encT, unsigned short* __restrict__ decT)
{
    if (unit < 1024) {              // ---- x cvt: 8 elems/thread ----
        const int i = unit * 256 + t;
        float4 a = ((const float4*)x)[2 * i];
        float4 b = ((const float4*)x)[2 * i + 1];
        ushort8 v;
        v[0] = f2bf(a.x); v[1] = f2bf(a.y); v[2] = f2bf(a.z); v[3] = f2bf(a.w);
        v[4] = f2bf(b.x); v[5] = f2bf(b.y); v[6] = f2bf(b.z); v[7] = f2bf(b.w);
        ((ushort8*)x_bf)[i] = v;
        return;
    }
    const float* in; unsigned short* out; int R, C, bx, by;
    if (unit < 1280) {              // enc [1024][256] -> encT [256][1024]
        const int bb = unit - 1024;
        in = enc; out = encT; R = 1024; C = 256; bx = bb % 8; by = bb / 8;
    } else {                        // dec [256][1024] -> decT [1024][256]
        const int bb = unit - 1280;
        in = dec; out = decT; R = 256; C = 1024; bx = bb % 32; by = bb / 32;
    }
    const int r0 = by * 32, c0 = bx * 32;
    const int tx = t % 32, ty = t / 32;       // 32 x 8
    __syncthreads();                // tile quiet from previous unit
    #pragma unroll
    for (int k = 0; k < 4; ++k) {
        const int lr = ty + k * 8;
        tile[lr][tx] = f2bf(in[(size_t)(r0 + lr) * C + c0 + tx]);
    }
    __syncthreads();
    #pragma unroll
    for (int k = 0; k < 4; ++k) {
        const int lc = ty + k * 8;
        out[(size_t)(c0 + lc) * R + r0 + tx] = tile[tx][lc];
    }
}

// =================== cooperative: prep + gemm1 + gemm2 ===================
__global__ __launch_bounds__(256) void coop_all(
    const float* __restrict__ x,               // [2048][1024] f32
    const float* __restrict__ enc_w,           // [1024][256] f32
    const float* __restrict__ dec_w,           // [256][1024] f32
    unsigned short* __restrict__ x_bf,         // ws [2048][1024] bf16
    unsigned short* __restrict__ encT,         // ws [256][1024] bf16
    unsigned short* __restrict__ decT,         // ws [1024][256] bf16
    unsigned short* __restrict__ me_bf,        // ws [2048][256] bf16
    float* __restrict__ m_e,                   // out [2048][256] f32
    float* __restrict__ m_d)                   // out [2048][1024] f32
{
    __shared__ __align__(16) unsigned char smem[81920];      // 80 KB union
    cg::grid_group grid = cg::this_grid();

    const int bid = blockIdx.x;
    const int t = threadIdx.x;
    const int lane = t & 63;
    const int l15 = lane & 15, l4 = lane >> 4;
    const int wid = t >> 6;
    const int wr = wid >> 1, wc = wid & 1;      // 2x2 wave grid

    // ---------------- phase P: prep (3 units per block) ----------------
    {
        unsigned short (*tile)[33] = (unsigned short(*)[33])smem;
        #pragma unroll
        for (int i = 0; i < 3; ++i)
            prep_unit(bid + 512 * i, t, tile, x, enc_w, dec_w, x_bf, encT, decT);
    }
    grid.sync();

    // ---------------- phase 1: m_e tile (32x32, BK=256, dbuf) ----------------
    {
        unsigned short* As1 = (unsigned short*)smem;            // [2][32*256] 32KB
        unsigned short* Bs1 = (unsigned short*)(smem + 32768);  // [2][32*256] 32KB
        constexpr int K = 1024, N = 256, BK = 256, NT = K / BK; // NT = 4
        const int brow = (bid >> 3) * 32, bcol = (bid & 7) * 32;
        const unsigned short* Ab = x_bf + (size_t)brow * K;
        const unsigned short* Bb = encT + (size_t)bcol * K;

        auto stage = [&](int kt, int buf) {
            #pragma unroll
            for (int c = 0; c < 4; ++c) {
                const int idx = c * 256 + t;
                const int row = idx >> 5;
                const int ch = (idx & 31) ^ (row & 31);
                gload_lds16(Ab + (size_t)row * K + kt * BK + ch * 8,
                            As1 + buf * 8192 + (idx & ~63) * 8);
            }
            #pragma unroll
            for (int c = 0; c < 4; ++c) {
                const int idx = c * 256 + t;
                const int row = idx >> 5;
                const int ch = (idx & 31) ^ (row & 31);
                gload_lds16(Bb + (size_t)row * K + kt * BK + ch * 8,
                            Bs1 + buf * 8192 + (idx & ~63) * 8);
            }
        };

        f32x4 acc = {0.f, 0.f, 0.f, 0.f};
        stage(0, 0);
        for (int kt = 0; kt < NT; ++kt) {
            __syncthreads();                 // stage(kt) landed
            if (kt + 1 < NT) stage(kt + 1, (kt + 1) & 1);
            const unsigned short* Asb = As1 + (kt & 1) * 8192;
            const unsigned short* Bsb = Bs1 + (kt & 1) * 8192;
            const int ra = wr * 16 + l15;
            const int rb = wc * 16 + l15;
            #pragma unroll
            for (int s = 0; s < 8; ++s) {    // 8 x 32-k MFMA steps
                const int ca = (s * 4 + l4) ^ (ra & 31);
                const bf16x8 aF = *(const bf16x8*)&Asb[ra * BK + ca * 8];
                const int cb = (s * 4 + l4) ^ (rb & 31);
                const bf16x8 bF = *(const bf16x8*)&Bsb[rb * BK + cb * 8];
                acc = __builtin_amdgcn_mfma_f32_16x16x32_bf16(aF, bF, acc, 0, 0, 0);
            }
        }
        #pragma unroll
        for (int reg = 0; reg < 4; ++reg) {
            const int row = brow + wr * 16 + l4 * 4 + reg;
            const int col = bcol + wc * 16 + l15;
            const float v = acc[reg];
            m_e[(size_t)row * N + col] = v;
            me_bf[(size_t)row * N + col] = f2bf(v);
        }
    }
    grid.sync();

    // ---------------- phase 2: m_d tile (32x128, K=256 LDS-resident) ---------
    {
        unsigned short* As2 = (unsigned short*)smem;            // [4][32*64] 16KB
        unsigned short* Bs2 = (unsigned short*)(smem + 16384);  // [4][128*64] 64KB
        constexpr int K = 256, N = 1024;
        const int brow = (bid >> 3) * 32, bcol = (bid & 7) * 128;

        #pragma unroll
        for (int kt = 0; kt < 4; ++kt) {
            stage_tile<32>(me_bf + (size_t)brow * K + kt * 64, K, As2 + kt * 2048, t);
            stage_tile<128>(decT + (size_t)bcol * K + kt * 64, K, Bs2 + kt * 8192, t);
        }
        __syncthreads();

        f32x4 acc[4];
        #pragma unroll
        for (int j = 0; j < 4; ++j) acc[j] = {0.f, 0.f, 0.f, 0.f};
        #pragma unroll
        for (int kt = 0; kt < 4; ++kt)
            #pragma unroll
            for (int s = 0; s < 2; ++s) {
                const int ra = wr * 16 + l15;
                const int cha = (s * 4 + l4) ^ (ra & 7);
                const bf16x8 aF = *(const bf16x8*)&As2[kt * 2048 + ra * 64 + cha * 8];
                #pragma unroll
                for (int j = 0; j < 4; ++j) {
                    const int rb = wc * 64 + j * 16 + l15;
                    const int chb = (s * 4 + l4) ^ (rb & 7);
                    const bf16x8 bF = *(const bf16x8*)&Bs2[kt * 8192 + rb * 64 + chb * 8];
                    acc[j] = __builtin_amdgcn_mfma_f32_16x16x32_bf16(aF, bF, acc[j], 0, 0, 0);
                }
            }
        #pragma unroll
        for (int j = 0; j < 4; ++j)
            #pragma unroll
            for (int reg = 0; reg < 4; ++reg) {
                const int row = brow + wr * 16 + l4 * 4 + reg;
                const int col = bcol + wc * 64 + j * 16 + l15;
                m_d[(size_t)row * N + col] = acc[j][reg];
            }
    }
}

// ================= r8 fallback kernels (3 dispatches) =================
__global__ __launch_bounds__(256) void prep(
    const float* __restrict__ x, const float* __restrict__ enc,
    const float* __restrict__ dec, unsigned short* __restrict__ x_bf,
    unsigned short* __restrict__ encT, unsigned short* __restrict__ decT)
{
    __shared__ unsigned short tile[32][33];
    prep_unit(blockIdx.x, threadIdx.x, tile, x, enc, dec, x_bf, encT, decT);
}

__global__ __launch_bounds__(256) void gemm1_bk256(
    const unsigned short* __restrict__ A, const unsigned short* __restrict__ Bt,
    float* __restrict__ C, unsigned short* __restrict__ Cbf)
{
    constexpr int N = 256, K = 1024, BK = 256, NT = K / BK;
    __shared__ __align__(16) unsigned short As[2][32 * BK];
    __shared__ __align__(16) unsigned short Bs[2][32 * BK];
    const int t = threadIdx.x;
    const int lane = t & 63;
    const int l15 = lane & 15, l4 = lane >> 4;
    const int wid = t >> 6;
    const int wr = wid >> 1, wc = wid & 1;
    const int brow = blockIdx.y * 32, bcol = blockIdx.x * 32;
    const unsigned short* Ab = A + (size_t)brow * K;
    const unsigned short* Bb = Bt + (size_t)bcol * K;
    auto stage = [&](int kt, int buf) {
        #pragma unroll
        for (int c = 0; c < 4; ++c) {
            const int idx = c * 256 + t;
            const int row = idx >> 5;
            const int ch = (idx & 31) ^ (row & 31);
            gload_lds16(Ab + (size_t)row * K + kt * BK + ch * 8,
                        &As[buf][(idx & ~63) * 8]);
        }
        #pragma unroll
        for (int c = 0; c < 4; ++c) {
            const int idx = c * 256 + t;
            const int row = idx >> 5;
            const int ch = (idx & 31) ^ (row & 31);
            gload_lds16(Bb + (size_t)row * K + kt * BK + ch * 8,
                        &Bs[buf][(idx & ~63) * 8]);
        }
    };
    f32x4 acc = {0.f, 0.f, 0.f, 0.f};
    stage(0, 0);
    for (int kt = 0; kt < NT; ++kt) {
        __syncthreads();
        if (kt + 1 < NT) stage(kt + 1, (kt + 1) & 1);
        const unsigned short* Asb = As[kt & 1];
        const unsigned short* Bsb = Bs[kt & 1];
        const int ra = wr * 16 + l15;
        const int rb = wc * 16 + l15;
        #pragma unroll
        for (int s = 0; s < 8; ++s) {
            const int ca = (s * 4 + l4) ^ (ra & 31);
            const bf16x8 aF = *(const bf16x8*)&Asb[ra * BK + ca * 8];
            const int cb = (s * 4 + l4) ^ (rb & 31);
            const bf16x8 bF = *(const bf16x8*)&Bsb[rb * BK + cb * 8];
            acc = __builtin_amdgcn_mfma_f32_16x16x32_bf16(aF, bF, acc, 0, 0, 0);
        }
    }
    #pragma unroll
    for (int reg = 0; reg < 4; ++reg) {
        const int row = brow + wr * 16 + l4 * 4 + reg;
        const int col = bcol + wc * 16 + l15;
        const float v = acc[reg];
        C[(size_t)row * N + col] = v;
        Cbf[(size_t)row * N + col] = f2bf(v);
    }
}

__global__ __launch_bounds__(256) void gemm2_kres128(
    const unsigned short* __restrict__ A, const unsigned short* __restrict__ B,
    float* __restrict__ C)
{
    constexpr int K = 256, N = 1024;
    __shared__ __align__(16) unsigned short As[4][32 * 64];
    __shared__ __align__(16) unsigned short Bs[4][128 * 64];
    const int t = threadIdx.x;
    const int lane = t & 63;
    const int l15 = lane & 15, l4 = lane >> 4;
    const int wid = t >> 6;
    const int wr = wid >> 1, wc = wid & 1;
    const int brow = blockIdx.y * 32, bcol = blockIdx.x * 128;
    #pragma unroll
    for (int kt = 0; kt < 4; ++kt) {
        stage_tile<32>(A + (size_t)brow * K + kt * 64, K, As[kt], t);
        stage_tile<128>(B + (size_t)bcol * K + kt * 64, K, Bs[kt], t);
    }
    __syncthreads();
    f32x4 acc[4];
    #pragma unroll
    for (int j = 0; j < 4; ++j) acc[j] = {0.f, 0.f, 0.f, 0.f};
    #pragma unroll
    for (int kt = 0; kt < 4; ++kt)
        #pragma unroll
        for (int s = 0; s < 2; ++s) {
            const int ra = wr * 16 + l15;
            const int cha = (s * 4 + l4) ^ (ra & 7);
            const bf16x8 aF = *(const bf16x8*)&As[kt][ra * 64 + cha * 8];
            #pragma unroll
            for (int j = 0; j < 4; ++j) {
                const int rb = wc * 64 + j * 16 + l15;
                const int chb = (s * 4 + l4) ^ (rb & 7);
                const bf16x8 bF = *(const bf16x8*)&Bs[kt][rb * 64 + chb * 8];
                acc[j] = __builtin_amdgcn_mfma_f32_16x16x32_bf16(aF, bF, acc[j], 0, 0, 0);
            }
        }
    #pragma unroll
    for (int j = 0; j < 4; ++j)
        #pragma unroll
        for (int reg = 0; reg < 4; ++reg) {
            const int row = brow + wr * 16 + l4 * 4 + reg;
            const int col = bcol + wc * 64 + j * 16 + l15;
            C[(size_t)row * N + col] = acc[j][reg];
        }
}

extern "C" void kernel_launch(void* const* d_in, const int* in_sizes, int n_in,
                              void* d_out, int out_size, void* d_ws, size_t ws_size,
                              hipStream_t stream) {
    const float* x     = (const float*)d_in[0];  // [2048, 1024]
    const float* enc_w = (const float*)d_in[1];  // [1024, 256]
    const float* dec_w = (const float*)d_in[2];  // [256, 1024]

    const int B = 2048, D = 1024, H = 256;
    float* m_d = (float*)d_out;
    float* m_e = (float*)d_out + (size_t)B * D;

    unsigned short* x_bf  = (unsigned short*)d_ws;            // [2048][1024]
    unsigned short* encT  = x_bf + (size_t)B * D;             // [256][1024]
    unsigned short* decT  = encT + (size_t)H * D;             // [1024][256]
    unsigned short* me_bf = decT + (size_t)D * H;             // [2048][256]

    void* args[] = {(void*)&x, (void*)&enc_w, (void*)&dec_w,
                    (void*)&x_bf, (void*)&encT, (void*)&decT,
                    (void*)&me_bf, (void*)&m_e, (void*)&m_d};
    hipError_t err = hipLaunchCooperativeKernel(
        reinterpret_cast<void*>(coop_all), dim3(512), dim3(256), args, 0, stream);
    if (err != hipSuccess) {
        // r8-proven 3-dispatch path
        prep<<<dim3(1536), dim3(256), 0, stream>>>(x, enc_w, dec_w, x_bf, encT, decT);
        gemm1_bk256<<<dim3(H / 32, B / 32), dim3(256), 0, stream>>>(x_bf, encT, m_e, me_bf);
        gemm2_kres128<<<dim3(D / 128, B / 32), dim3(256), 0, stream>>>(me_bf, decT, m_d);
    }
}

// Round 11
// 21.348 us; speedup vs baseline: 7.2645x; 7.2645x over previous
//
#include <hip/hip_runtime.h>

// SNN autoencoder collapses to: m_e = x @ enc_w ; m_d = m_e @ dec_w
// (spike state is exactly {0,1}, so 0.9*s - 0.9*(s>0.9) == 0 every step;
//  membranes are recomputed from the constant input current each step).
// Output: d_out = [m_d (2048x1024) | m_e (2048x256)], fp32.
//
// 3 dispatches (r8 structure + T1 XCD-keyed row ownership):
//   prep   : x->bf16 (XCD-remapped), enc/dec transpose (1536 blocks)
//   gemm1  : 32x32 tiles, BK=256, dbuf; strip = (bid&7)*8 + (bid>>3)&7
//   gemm2  : 32x128 tiles, K=256 LDS-resident; same strip mapping
// XCD x owns rows [x*256, x*256+256) of x_bf/m_e/me_bf across all kernels ->
// strip re-reads and me_bf reads are XCD-local L2 hits instead of L3.
// (r9 per-tile atomics = 53us, r10 grid.sync = 137us: in-kernel cross-block
//  sync is >=10x worse than a dispatch boundary on 8-XCD CDNA4. Closed.)

typedef __attribute__((ext_vector_type(8))) short bf16x8;
typedef __attribute__((ext_vector_type(4))) float f32x4;
typedef __attribute__((ext_vector_type(8))) unsigned short ushort8;

__device__ __forceinline__ unsigned short f2bf(float f) {
    unsigned u = __builtin_bit_cast(unsigned, f);
    unsigned r = u + 0x7FFFu + ((u >> 16) & 1u);   // RNE
    return (unsigned short)(r >> 16);
}

__device__ __forceinline__ void gload_lds16(const void* src, void* dst) {
    __builtin_amdgcn_global_load_lds(
        (const __attribute__((address_space(1))) void*)src,
        (__attribute__((address_space(3))) void*)dst, 16, 0, 0);
}

// ---- stage ROWS x 64 bf16 tile (8 chunks/row, XOR-swizzled source, rule #21) ----
template <int ROWS>
__device__ __forceinline__ void stage_tile(const unsigned short* __restrict__ g,
                                           int ld, unsigned short* lds, int t) {
    #pragma unroll
    for (int c = 0; c < ROWS / 32; ++c) {
        const int idx = c * 256 + t;          // 16B-chunk index in tile
        const int row = idx >> 3;
        const int chunk = (idx & 7) ^ (row & 7);
        const unsigned short* src = g + (size_t)row * ld + chunk * 8;
        unsigned short* dst = lds + (size_t)(idx & ~63) * 8;  // wave-uniform base
        gload_lds16(src, dst);
    }
}

// ---- one prep unit: unit<1024 x-cvt | 1024..1279 encT | 1280..1535 decT ----
__device__ __forceinline__ void prep_unit(
    int unit, int t, unsigned short (*tile)[33],
    const float* __restrict__ x, const float* __restrict__ enc,
    const float* __restrict__ dec, unsigned short* __restrict__ x_bf,
    unsigned short* __restrict__ encT, unsigned short* __restrict__ decT)
{
    if (unit < 1024) {              // ---- x cvt: 8 elems/thread ----
        const int i = unit * 256 + t;
        float4 a = ((const float4*)x)[2 * i];
        float4 b = ((const float4*)x)[2 * i + 1];
        ushort8 v;
        v[0] = f2bf(a.x); v[1] = f2bf(a.y); v[2] = f2bf(a.z); v[3] = f2bf(a.w);
        v[4] = f2bf(b.x); v[5] = f2bf(b.y); v[6] = f2bf(b.z); v[7] = f2bf(b.w);
        ((ushort8*)x_bf)[i] = v;
        return;
    }
    const float* in; unsigned short* out; int R, C, bx, by;
    if (unit < 1280) {              // enc [1024][256] -> encT [256][1024]
        const int bb = unit - 1024;
        in = enc; out = encT; R = 1024; C = 256; bx = bb % 8; by = bb / 8;
    } else {                        // dec [256][1024] -> decT [1024][256]
        const int bb = unit - 1280;
        in = dec; out = decT; R = 256; C = 1024; bx = bb % 32; by = bb / 32;
    }
    const int r0 = by * 32, c0 = bx * 32;
    const int tx = t % 32, ty = t / 32;       // 32 x 8
    #pragma unroll
    for (int k = 0; k < 4; ++k) {
        const int lr = ty + k * 8;
        tile[lr][tx] = f2bf(in[(size_t)(r0 + lr) * C + c0 + tx]);
    }
    __syncthreads();
    #pragma unroll
    for (int k = 0; k < 4; ++k) {
        const int lc = ty + k * 8;
        out[(size_t)(c0 + lc) * R + r0 + tx] = tile[tx][lc];
    }
}

// ---------------- prep (1536 blocks; x-cvt XCD-remapped) ----------------
__global__ __launch_bounds__(256) void prep(
    const float* __restrict__ x, const float* __restrict__ enc,
    const float* __restrict__ dec, unsigned short* __restrict__ x_bf,
    unsigned short* __restrict__ encT, unsigned short* __restrict__ decT)
{
    __shared__ unsigned short tile[32][33];
    const int bid = blockIdx.x;
    // x-cvt remap: XCD (bid&7) writes x_bf rows [xcd*256, xcd*256+256)
    const int unit = (bid < 1024) ? ((bid & 7) * 128 + (bid >> 3)) : bid;
    prep_unit(unit, threadIdx.x, tile, x, enc, dec, x_bf, encT, decT);
}

// ---------------- GEMM1: 32x32 tiles, BK=256, dbuf, XCD-keyed strips ---------
__global__ __launch_bounds__(256) void gemm1_bk256(
    const unsigned short* __restrict__ A,   // x_bf [2048][1024] bf16
    const unsigned short* __restrict__ Bt,  // encT [256][1024] bf16
    float* __restrict__ C,                  // m_e  [2048][256] f32
    unsigned short* __restrict__ Cbf)       // me_bf[2048][256] bf16
{
    constexpr int N = 256, K = 1024, BK = 256, NT = K / BK;  // NT = 4
    __shared__ __align__(16) unsigned short As[2][32 * BK];
    __shared__ __align__(16) unsigned short Bs[2][32 * BK];

    const int t = threadIdx.x;
    const int lane = t & 63;
    const int l15 = lane & 15, l4 = lane >> 4;
    const int wid = t >> 6;
    const int wr = wid >> 1, wc = wid & 1;          // 2x2 waves, WM=WN=16
    // XCD-keyed remap (bijective on [0,512)): XCD x owns strips x*8..x*8+7
    const int bid = blockIdx.x;
    const int idx = bid >> 3;
    const int strip = (bid & 7) * 8 + (idx & 7);    // 0..63
    const int brow = strip * 32, bcol = (idx >> 3) * 32;

    const unsigned short* Ab = A + (size_t)brow * K;
    const unsigned short* Bb = Bt + (size_t)bcol * K;

    // tile [32 rows][256 k] bf16 = 1024 x 16B chunks, 32 chunks/row, 4/thread
    auto stage = [&](int kt, int buf) {
        #pragma unroll
        for (int c = 0; c < 4; ++c) {
            const int idx2 = c * 256 + t;
            const int row = idx2 >> 5;
            const int ch = (idx2 & 31) ^ (row & 31);
            gload_lds16(Ab + (size_t)row * K + kt * BK + ch * 8,
                        &As[buf][(idx2 & ~63) * 8]);
        }
        #pragma unroll
        for (int c = 0; c < 4; ++c) {
            const int idx2 = c * 256 + t;
            const int row = idx2 >> 5;
            const int ch = (idx2 & 31) ^ (row & 31);
            gload_lds16(Bb + (size_t)row * K + kt * BK + ch * 8,
                        &Bs[buf][(idx2 & ~63) * 8]);
        }
    };

    f32x4 acc = {0.f, 0.f, 0.f, 0.f};
    stage(0, 0);
    for (int kt = 0; kt < NT; ++kt) {
        __syncthreads();            // stage(kt) landed; other buffer reads done
        if (kt + 1 < NT) stage(kt + 1, (kt + 1) & 1);
        const unsigned short* Asb = As[kt & 1];
        const unsigned short* Bsb = Bs[kt & 1];
        const int ra = wr * 16 + l15;
        const int rb = wc * 16 + l15;
        #pragma unroll
        for (int s = 0; s < 8; ++s) {           // 8 x 32-k MFMA steps
            const int ca = (s * 4 + l4) ^ (ra & 31);
            const bf16x8 aF = *(const bf16x8*)&Asb[ra * BK + ca * 8];
            const int cb = (s * 4 + l4) ^ (rb & 31);
            const bf16x8 bF = *(const bf16x8*)&Bsb[rb * BK + cb * 8];
            acc = __builtin_amdgcn_mfma_f32_16x16x32_bf16(aF, bF, acc, 0, 0, 0);
        }
    }

    #pragma unroll
    for (int reg = 0; reg < 4; ++reg) {
        const int row = brow + wr * 16 + l4 * 4 + reg;
        const int col = bcol + wc * 16 + l15;
        const float v = acc[reg];
        C[(size_t)row * N + col] = v;
        Cbf[(size_t)row * N + col] = f2bf(v);
    }
}

// ---------------- GEMM2: K=256 LDS-resident, BN=128, XCD-keyed strips --------
__global__ __launch_bounds__(256) void gemm2_kres128(
    const unsigned short* __restrict__ A,   // [2048][256] bf16 (me_bf)
    const unsigned short* __restrict__ B,   // [1024][256] bf16 (decT)
    float* __restrict__ C)                  // [2048][1024] f32 (m_d)
{
    constexpr int K = 256, N = 1024;
    __shared__ __align__(16) unsigned short As[4][32 * 64];   // 16 KB
    __shared__ __align__(16) unsigned short Bs[4][128 * 64];  // 64 KB

    const int t = threadIdx.x;
    const int lane = t & 63;
    const int l15 = lane & 15, l4 = lane >> 4;
    const int wid = t >> 6;
    const int wr = wid >> 1, wc = wid & 1;          // 2x2 waves: WM=16, WN=64
    // same XCD-keyed strip mapping as gemm1: me_bf reads are XCD-local
    const int bid = blockIdx.x;
    const int idx = bid >> 3;
    const int strip = (bid & 7) * 8 + (idx & 7);    // 0..63
    const int brow = strip * 32, bcol = (idx >> 3) * 128;

    #pragma unroll
    for (int kt = 0; kt < 4; ++kt) {
        stage_tile<32>(A + (size_t)brow * K + kt * 64, K, As[kt], t);
        stage_tile<128>(B + (size_t)bcol * K + kt * 64, K, Bs[kt], t);
    }
    __syncthreads();

    f32x4 acc[4];
    #pragma unroll
    for (int j = 0; j < 4; ++j) acc[j] = {0.f, 0.f, 0.f, 0.f};

    #pragma unroll
    for (int kt = 0; kt < 4; ++kt)
        #pragma unroll
        for (int s = 0; s < 2; ++s) {
            const int ra = wr * 16 + l15;
            const int cha = (s * 4 + l4) ^ (ra & 7);
            const bf16x8 aF = *(const bf16x8*)&As[kt][ra * 64 + cha * 8];
            #pragma unroll
            for (int j = 0; j < 4; ++j) {
                const int rb = wc * 64 + j * 16 + l15;
                const int chb = (s * 4 + l4) ^ (rb & 7);
                const bf16x8 bF = *(const bf16x8*)&Bs[kt][rb * 64 + chb * 8];
                acc[j] = __builtin_amdgcn_mfma_f32_16x16x32_bf16(aF, bF, acc[j], 0, 0, 0);
            }
        }

    #pragma unroll
    for (int j = 0; j < 4; ++j)
        #pragma unroll
        for (int reg = 0; reg < 4; ++reg) {
            const int row = brow + wr * 16 + l4 * 4 + reg;
            const int col = bcol + wc * 64 + j * 16 + l15;
            C[(size_t)row * N + col] = acc[j][reg];
        }
}

// ---------------- fp32 fallback ----------------
#define BKF 32
#define PADF 4
template <int BM, int BN, int TM, int TN>
__global__ __launch_bounds__(256) void gemm_f32(
    const float* __restrict__ A, const float* __restrict__ B,
    float* __restrict__ C, int M, int N, int K)
{
    __shared__ float As[BKF][BM + PADF];
    __shared__ float Bs[BKF][BN + PADF];
    const int t = threadIdx.x;
    const int brow = blockIdx.y * BM, bcol = blockIdx.x * BN;
    constexpr int NTX = BN / TN;
    const int tx = t % NTX, ty = t / NTX;
    float acc[TM][TN];
    #pragma unroll
    for (int i = 0; i < TM; ++i)
        #pragma unroll
        for (int j = 0; j < TN; ++j) acc[i][j] = 0.f;
    for (int k0 = 0; k0 < K; k0 += BKF) {
        #pragma unroll
        for (int v = t; v < BM * BKF / 4; v += 256) {
            const int row = v / (BKF / 4), kv = v % (BKF / 4);
            const float4 val = *(const float4*)&A[(size_t)(brow + row) * K + k0 + kv * 4];
            As[kv * 4 + 0][row] = val.x; As[kv * 4 + 1][row] = val.y;
            As[kv * 4 + 2][row] = val.z; As[kv * 4 + 3][row] = val.w;
        }
        #pragma unroll
        for (int v = t; v < BKF * BN / 4; v += 256) {
            const int kk = v / (BN / 4), cv = v % (BN / 4);
            *(float4*)&Bs[kk][cv * 4] = *(const float4*)&B[(size_t)(k0 + kk) * N + bcol + cv * 4];
        }
        __syncthreads();
        #pragma unroll
        for (int k = 0; k < BKF; ++k) {
            float a[TM], b[TN];
            #pragma unroll
            for (int i = 0; i < TM; ++i) a[i] = As[k][ty * TM + i];
            #pragma unroll
            for (int j = 0; j < TN; ++j) b[j] = Bs[k][tx * TN + j];
            #pragma unroll
            for (int i = 0; i < TM; ++i)
                #pragma unroll
                for (int j = 0; j < TN; ++j) acc[i][j] = fmaf(a[i], b[j], acc[i][j]);
        }
        __syncthreads();
    }
    #pragma unroll
    for (int i = 0; i < TM; ++i)
        #pragma unroll
        for (int j = 0; j < TN; ++j)
            C[(size_t)(brow + ty * TM + i) * N + bcol + tx * TN + j] = acc[i][j];
}

extern "C" void kernel_launch(void* const* d_in, const int* in_sizes, int n_in,
                              void* d_out, int out_size, void* d_ws, size_t ws_size,
                              hipStream_t stream) {
    const float* x     = (const float*)d_in[0];  // [2048, 1024]
    const float* enc_w = (const float*)d_in[1];  // [1024, 256]
    const float* dec_w = (const float*)d_in[2];  // [256, 1024]

    const int B = 2048, D = 1024, H = 256;
    float* m_d = (float*)d_out;
    float* m_e = (float*)d_out + (size_t)B * D;

    const size_t need = (size_t)B * D * 2 + (size_t)D * H * 2 * 2 + (size_t)B * H * 2;
    if (ws_size >= need) {
        unsigned short* x_bf  = (unsigned short*)d_ws;            // [2048][1024]
        unsigned short* encT  = x_bf + (size_t)B * D;             // [256][1024]
        unsigned short* decT  = encT + (size_t)H * D;             // [1024][256]
        unsigned short* me_bf = decT + (size_t)D * H;             // [2048][256]

        prep<<<dim3(1536), dim3(256), 0, stream>>>(x, enc_w, dec_w, x_bf, encT, decT);
        gemm1_bk256<<<dim3(512), dim3(256), 0, stream>>>(x_bf, encT, m_e, me_bf);
        gemm2_kres128<<<dim3(512), dim3(256), 0, stream>>>(me_bf, decT, m_d);
    } else {
        gemm_f32<64, 32, 4, 2><<<dim3(H / 32, B / 64), dim3(256), 0, stream>>>(x, enc_w, m_e, B, H, D);
        gemm_f32<64, 64, 4, 4><<<dim3(D / 64, B / 64), dim3(256), 0, stream>>>(m_e, dec_w, m_d, B, D, H);
    }
}